// Round 17
// baseline (539.812 us; speedup 1.0000x reference)
//
#include <hip/hip_runtime.h>
#include <hip/hip_bf16.h>
#include <math.h>

#define NB 16
#define ND 256
#define NL 200
#define NT 1000

typedef unsigned short ushort_t;
typedef __bf16 bf16x8 __attribute__((ext_vector_type(8)));
typedef float f32x4 __attribute__((ext_vector_type(4)));

// ---- workspace layout (float offsets) ----
#define OFF_UT    0u         // U_T fp32 [2][16][200][256]   1638400 floats
#define OFF_CT    4000000u   // Ct fp32 [2][8][3][256]       12288 floats
#define OFF_SK    4966400u   // exclusive cumsum [16][200]   3200
#define OFF_FL    4981936u   // frame_lengths int            16
#define OFF_GT    11535552u  // Gt bf16 [b][256][800]        1638400 floats
#define OFF_WOT   15221952u  // WoT bf16 [512][256]          65536 floats

__device__ __forceinline__ float silu_f(float x){ return x / (1.f + __expf(-x)); }
__device__ __forceinline__ ushort_t f2bf(float x){
  __hip_bfloat16 h = __float2bfloat16(x);
  return *(ushort_t*)&h;
}

// ====== KERNEL 1 (input-only): prep(16) | U-GEMM(416) | Gt(256) | WoT(128) | Ct(1)
// U-GEMM: U_T[br][b][l][i] = bp[i] + sum_d Wp[i][d]*ph[b][d][l]  (fp32,
// reference op order). Conv+base move into k_wv's front-end (reads U_T/Ct).
__global__ __launch_bounds__(256) void k_pre(
    const float* __restrict__ dur, const float* __restrict__ ph,
    const float* __restrict__ Wp_w, const float* __restrict__ C_w, const float* __restrict__ bp_w,
    const float* __restrict__ Wp_c, const float* __restrict__ C_c, const float* __restrict__ bp_c,
    const float* __restrict__ Wo, const float* __restrict__ Lw,
    float* __restrict__ sk_ws, int* __restrict__ fl_ws,
    float* __restrict__ o_fm, float* __restrict__ o_fl,
    float* __restrict__ U_T, float* __restrict__ Ct,
    ushort_t* __restrict__ WoT, ushort_t* __restrict__ Gt)
{
  __shared__ __align__(16) unsigned char smem[36864];
  int bid = blockIdx.x, tid = threadIdx.x;

  if (bid < 16){
    // ---- prep: cumsum, frame_lengths, frame_mask ----
    int b = bid;
    float* sdur = (float*)smem;
    float* ssk  = sdur + 256;
    int*   sfl  = (int*)(ssk + 256);
    if (tid < NL) sdur[tid] = dur[b*NL + tid];
    __syncthreads();
    if (tid == 0){
      float run = 0.f;
      for (int l = 0; l < NL; ++l){ ssk[l] = run; run += sdur[l]; }
      int fl = (int)rintf(run);          // round-half-even, matches jnp.round
      fl = fl < 0 ? 0 : (fl > NT ? NT : fl);
      sfl[0] = fl; fl_ws[b] = fl; o_fl[b] = (float)fl;
    }
    __syncthreads();
    if (tid < NL) sk_ws[b*NL + tid] = ssk[tid];
    int flv = sfl[0];
    for (int t = tid; t < NT; t += 256) o_fm[b*NT + t] = (t < flv) ? 1.f : 0.f;
  } else if (bid < 432){
    // ---- U-GEMM: one (b, 16-l chunk, branch) per block ----
    int r = bid - 16;                    // 416 = 16b x 13x x 2br
    int br = r & 1;
    int bx = r >> 1;
    int x = bx % 13, b = bx / 13;
    int l0 = x*16;
    float* phs = (float*)smem;           // [18][256] 18432 B
    {
      const float* pr = ph + ((size_t)b*ND + tid)*NL;
      #pragma unroll
      for (int j = 0; j < 18; ++j){
        int l = l0 - 1 + j;
        phs[j*256 + tid] = (l >= 0 && l < NL) ? pr[l] : 0.f;
      }
    }
    __syncthreads();
    int i = tid;
    float u[18];
    float bb = (br ? bp_c : bp_w)[i];
    #pragma unroll
    for (int j = 0; j < 18; ++j) u[j] = bb;
    const float4* wr = (const float4*)((br ? Wp_c : Wp_w) + (size_t)i*ND);
    for (int d4 = 0; d4 < 64; ++d4){
      float4 a = wr[d4];
      #pragma unroll
      for (int j = 0; j < 18; ++j){
        float4 p = *(const float4*)&phs[j*256 + d4*4];
        u[j] += a.x*p.x + a.y*p.y + a.z*p.z + a.w*p.w;
      }
    }
    // store rows l = l0..l0+15 (j=1..16), coalesced across i
    float* Ub = U_T + ((size_t)(br*16 + b))*NL*ND;
    #pragma unroll
    for (int j = 1; j <= 16; ++j){
      int l = l0 - 1 + j;
      if (l < NL) Ub[(size_t)l*ND + i] = u[j];
    }
  } else if (bid < 688){
    // ---- Gt = Lw x ph (per b,q), coalesced quarter-K self-staging ----
    int r = bid - 432;                   // (xb, yb, b, q)
    int xb = r & 1, yb = (r >> 1) & 1, bq = r >> 2;
    int b = bq >> 2, q = bq & 3;
    int m0 = yb * 128;                   // n dim
    int n0 = xb * 128;                   // l dim
    int lane = tid & 63, wave = tid >> 6;
    int wm = wave >> 1, wn = wave & 1;
    int col = lane & 15, kg4 = lane >> 4;
    ushort_t (*Asub)[72] = (ushort_t (*)[72])smem;             // 18432 B
    ushort_t (*Bsub)[72] = (ushort_t (*)[72])(smem + 18432);   // 18432 B
    int na = lane*2;                     // n-pair this lane owns

    f32x4 acc[4][4] = {};
    for (int kq = 0; kq < 4; ++kq){
      int d0 = kq*64;
      for (int rep = 0; rep < 16; ++rep){
        int dk = wave*16 + rep;
        float2 v = *(const float2*)(Lw + ((size_t)(q*256 + d0 + dk))*ND + m0 + na);
        Asub[na    ][dk] = f2bf(v.x);
        Asub[na + 1][dk] = f2bf(v.y);
      }
      for (int rep = 0; rep < 16; ++rep){
        int dk = wave*16 + rep;
        int l = n0 + na;
        float2 v; v.x = 0.f; v.y = 0.f;
        if (l < NL)
          v = *(const float2*)(ph + ((size_t)b*ND + d0 + dk)*NL + l);
        Bsub[na    ][dk] = f2bf(v.x);
        Bsub[na + 1][dk] = f2bf(v.y);
      }
      __syncthreads();
      for (int kt = 0; kt < 2; ++kt){
        int k0 = kt*32;
        bf16x8 afr[4], bfr[4];
        #pragma unroll
        for (int i = 0; i < 4; ++i)
          afr[i] = *(const bf16x8*)&Asub[wm*64 + i*16 + col][k0 + kg4*8];
        #pragma unroll
        for (int j = 0; j < 4; ++j)
          bfr[j] = *(const bf16x8*)&Bsub[wn*64 + j*16 + col][k0 + kg4*8];
        #pragma unroll
        for (int i = 0; i < 4; ++i)
          #pragma unroll
          for (int j = 0; j < 4; ++j)
            acc[i][j] = __builtin_amdgcn_mfma_f32_16x16x32_bf16(afr[i], bfr[j], acc[i][j], 0, 0, 0);
      }
      __syncthreads();
    }
    ushort_t (*st2)[136] = (ushort_t (*)[136])smem;            // 34816 B
    int rq = lane >> 4;
    #pragma unroll
    for (int i = 0; i < 4; ++i){
      #pragma unroll
      for (int rr = 0; rr < 4; ++rr){
        int rl = wm*64 + i*16 + rq*4 + rr;
        #pragma unroll
        for (int j = 0; j < 4; ++j){
          int cl = wn*64 + j*16 + col;
          st2[rl][cl] = f2bf(acc[i][j][rr]);
        }
      }
    }
    __syncthreads();
    #pragma unroll
    for (int rep = 0; rep < 8; ++rep){
      int row = rep*16 + (tid >> 4);
      int ch  = tid & 15;
      int l   = n0 + ch*8;
      if (l < NL){
        int n = m0 + row;
        *(uint4*)(Gt + ((size_t)(b*ND + n))*800 + q*NL + l) = *(const uint4*)&st2[row][ch*8];
      }
    }
  } else if (bid < 816){
    // ---- WoT pack: WoT[n][k] = Wo[k][n] bf16 ----
    int base_id = (bid - 688)*256 + tid;
    #pragma unroll
    for (int rep = 0; rep < 4; ++rep){
      int gid = rep*32768 + base_id;     // 131072 total
      int n = gid >> 8, k = gid & 255;
      WoT[gid] = f2bf(Wo[(size_t)k*512 + n]);
    }
  } else {
    // ---- Ct transpose: Ct[br][oc][k][i] = C[oc][i][k] (12288 floats) ----
    for (int idx = tid; idx < 12288; idx += 256){
      int br = idx / 6144, r = idx % 6144;
      int oc = r / 768, k = (r % 768) / 256, i = r & 255;
      Ct[idx] = (br ? C_c : C_w)[((size_t)oc*ND + i)*3 + k];
    }
  }
}

// ====== K2: conv+base front-end + softmax + V-GEMM + out-GEMM per (b, 64-t tile)
// TT=64, 1024 threads, grid (16,16) = 256 blocks = 1/CU. Front-end computes
// h = conv(Ct, U_T) fp32 (reference order, pad rows skipped) + base MLP into
// LDS; phase 1 reads base from LDS. Eliminates stage-2 kernel entirely.
#define AP 808
#define TT 64
__global__ __launch_bounds__(1024, 4) void k_wv_fused(
    const float* __restrict__ U_T,      // [2][16][200][256] fp32
    const float* __restrict__ Ct,       // [2][8][3][256] fp32
    const float* __restrict__ dur,
    const float* __restrict__ sk_ws,
    const float* __restrict__ cbw, const float* __restrict__ cbc,
    const float* __restrict__ mbw, const float* __restrict__ mbc,
    const int* __restrict__ fl_ws,
    const float* __restrict__ Mw, const float* __restrict__ Mc,
    const ushort_t* __restrict__ Gt,    // [16][256][800] bf16
    const float* __restrict__ Lc,       // [8][256]
    const float* __restrict__ lbc,      // [256]
    const float* __restrict__ lbw,      // [256]
    const ushort_t* __restrict__ WoT,   // [512][256] bf16
    const float* __restrict__ bo,       // [512]
    float* __restrict__ wout,
    float* __restrict__ o_mean, float* __restrict__ o_lstd)
{
  __shared__ ushort_t As[TT*AP];   // 103.4 KB w-tile [t_local][k=q*200+l]
  __shared__ float    wcs[TT][8];  // 2 KB per-t wc
  __shared__ float    baseL[NL][9];// 7.2 KB padded base table
  int b = blockIdx.x;              // batch -> XCD = b%8
  int m0 = blockIdx.y * TT;        // t tile (16 tiles cover 0..1023)
  int tid = threadIdx.x, lane = tid & 63, wave = tid >> 6;   // 16 waves
  int col = lane & 15, kg4 = lane >> 4;
  int fl = fl_ws[b];

  // ---------------- early-out: fully-masked tile ----------------
  if (fl <= m0){
    for (int idx = tid; idx < TT*4*50; idx += 1024){
      int tl = idx / 200;
      int rqs = idx - tl*200;
      int q = rqs / 50, seg = rqs - q*50;
      int t = m0 + tl;
      if (t < NT)
        *(float4*)&wout[(((size_t)(b*4 + q))*NT + t)*NL + seg*4] = make_float4(0,0,0,0);
    }
    for (int idx = tid; idx < 512*16; idx += 1024){
      int s = idx >> 4, j = idx & 15;
      int t0 = m0 + j*4;
      if (t0 + 3 < NT){
        float v = bo[s];
        float4 v4 = make_float4(v, v, v, v);
        if (s < ND) *(float4*)&o_mean[((size_t)b*ND + s)*NT + t0] = v4;
        else        *(float4*)&o_lstd[((size_t)b*ND + (s - ND))*NT + t0] = v4;
      }
    }
    return;
  }

  // -------- front-end: h = conv(Ct, U_T) + base MLP, all in LDS ----------
  {
    float* hL = (float*)As;            // [200][16] f32 aliases As (12.8 KB)
    for (int idx = tid; idx < NL*16; idx += 1024){
      int l = idx >> 4, u = idx & 15;
      int br = u >> 3, oc = u & 7;
      const float* Cb = Ct + ((size_t)(br*8 + oc))*3*256;
      const float* Ub = U_T + ((size_t)(br*16 + b))*NL*ND;
      float val = (br ? cbc : cbw)[oc];
      #pragma unroll
      for (int k = 0; k < 3; ++k){
        int ll = l + k - 1;
        if (ll < 0 || ll >= NL) continue;   // SAME zero-pad: drop term
        const float4* cr = (const float4*)(Cb + k*256);
        const float4* ur = (const float4*)(Ub + (size_t)ll*ND);
        float acc = 0.f;
        #pragma unroll 8
        for (int d = 0; d < 64; ++d){
          float4 c4 = cr[d], u4 = ur[d];
          acc += c4.x*u4.x + c4.y*u4.y + c4.z*u4.z + c4.w*u4.w;
        }
        val += acc;
      }
      float pm = (dur[b*NL + l] > 0.5f) ? 1.f : 0.f;
      hL[l*16 + u] = silu_f(val) * pm;
    }
    __syncthreads();
    if (tid < NL){
      int l = tid;
      float dl  = dur[b*NL + l];
      float pm  = (dl > 0.5f) ? 1.f : 0.f;
      float skl = sk_ws[b*NL + l];
      float c1[4], c2[2];
      #pragma unroll
      for (int q = 0; q < 4; ++q) c1[q] = mbw[q] + dl*Mw[4 + q] - skl*Mw[q];
      #pragma unroll
      for (int p = 0; p < 2; ++p) c2[p] = mbc[p] + dl*Mc[2 + p] - skl*Mc[p];
      #pragma unroll
      for (int j = 0; j < 8; ++j){
        float hwv = hL[l*16 + j], hcv = hL[l*16 + 8 + j];
        #pragma unroll
        for (int q = 0; q < 4; ++q) c1[q] += hwv*Mw[(2 + j)*4 + q];
        #pragma unroll
        for (int p = 0; p < 2; ++p) c2[p] += hcv*Mc[(2 + j)*2 + p];
      }
      baseL[l][0] = c1[0]; baseL[l][1] = c1[1];
      baseL[l][2] = c1[2]; baseL[l][3] = c1[3];
      baseL[l][4] = c2[0]; baseL[l][5] = c2[1];
      baseL[l][6] = pm;    baseL[l][7] = 0.f;
    }
    __syncthreads();   // hL (As alias) dead; baseL live
  }

  // ---------------- phase 1: softmax, lane owns l = lane*4..lane*4+3 ----------
  int l0 = lane*4;
  bool lv = (l0 < NL);             // lanes 0..49 active

  #pragma unroll
  for (int s = 0; s < 4; ++s){
    int tl = wave*4 + s, t = m0 + tl;
    if (t < fl) continue;
    for (int k = l0; k < 800; k += 256){
      uint2 zz2; zz2.x = 0u; zz2.y = 0u;
      *(uint2*)&As[tl*AP + k] = zz2;
    }
    if (lane < 8) wcs[tl][lane] = 0.f;
    if (t < NT && lv){
      float4 z4 = make_float4(0,0,0,0);
      #pragma unroll
      for (int q = 0; q < 4; ++q)
        *(float4*)&wout[(((size_t)(b*4 + q))*NT + t)*NL + l0] = z4;
    }
  }

  float b0a[4][4], b1x[4], b1y[4], pmv[4];
  #pragma unroll
  for (int e = 0; e < 4; ++e){
    if (lv){
      const float* bl = &baseL[l0 + e][0];
      b0a[e][0] = bl[0]; b0a[e][1] = bl[1]; b0a[e][2] = bl[2]; b0a[e][3] = bl[3];
      b1x[e] = bl[4]; b1y[e] = bl[5]; pmv[e] = bl[6];
    } else {
      b0a[e][0] = b0a[e][1] = b0a[e][2] = b0a[e][3] = 0.f;
      b1x[e] = 0.f; b1y[e] = 0.f; pmv[e] = 0.f;
    }
  }
  float mwq[4] = {Mw[0], Mw[1], Mw[2], Mw[3]};
  float mcp[2] = {Mc[0], Mc[1]};

  for (int sp = 0; sp < 2; ++sp){
    int tl0 = wave*4 + sp*2;
    int t0 = m0 + tl0;
    if (t0 >= fl) break;
    bool a1 = (t0 + 1 < fl);
    float tf[2] = {(float)(t0 + 1), (float)(t0 + 2)};

    float z[2][4][4], mx[2][4];
    #pragma unroll
    for (int u = 0; u < 2; ++u)
      #pragma unroll
      for (int q = 0; q < 4; ++q) mx[u][q] = -INFINITY;
    #pragma unroll
    for (int e = 0; e < 4; ++e){
      #pragma unroll
      for (int u = 0; u < 2; ++u){
        #pragma unroll
        for (int q = 0; q < 4; ++q){
          float sv = silu_f(b0a[e][q] + tf[u]*mwq[q]);
          float zv = (pmv[e] > 0.f) ? sv : -INFINITY;
          z[u][e][q] = zv;
          mx[u][q] = fmaxf(mx[u][q], zv);
        }
      }
    }
    #pragma unroll
    for (int u = 0; u < 2; ++u)
      #pragma unroll
      for (int q = 0; q < 4; ++q){
        float v = mx[u][q];
        #pragma unroll
        for (int off = 32; off; off >>= 1) v = fmaxf(v, __shfl_xor(v, off));
        mx[u][q] = v;
      }
    float is4[2][4] = {{0,0,0,0},{0,0,0,0}};
    #pragma unroll
    for (int e = 0; e < 4; ++e){
      #pragma unroll
      for (int u = 0; u < 2; ++u){
        #pragma unroll
        for (int q = 0; q < 4; ++q){
          float ev = (pmv[e] > 0.f) ? __expf(z[u][e][q] - mx[u][q]) : 0.f;
          z[u][e][q] = ev;
          is4[u][q] += ev;
        }
      }
    }
    #pragma unroll
    for (int u = 0; u < 2; ++u)
      #pragma unroll
      for (int q = 0; q < 4; ++q){
        float v = is4[u][q];
        #pragma unroll
        for (int off = 32; off; off >>= 1) v += __shfl_xor(v, off);
        is4[u][q] = 1.f / v;
      }
    float cv[2][4][2];
    #pragma unroll
    for (int e = 0; e < 4; ++e)
      #pragma unroll
      for (int u = 0; u < 2; ++u){
        cv[u][e][0] = silu_f(b1x[e] + tf[u]*mcp[0]);
        cv[u][e][1] = silu_f(b1y[e] + tf[u]*mcp[1]);
      }
    float wc[2][8];
    #pragma unroll
    for (int u = 0; u < 2; ++u)
      #pragma unroll
      for (int x = 0; x < 8; ++x) wc[u][x] = 0.f;
    #pragma unroll
    for (int u = 0; u < 2; ++u){
      bool act = (u == 0) || a1;
      int t = t0 + u, tl = tl0 + u;
      #pragma unroll
      for (int q = 0; q < 4; ++q){
        float w0 = z[u][0][q]*is4[u][q];
        float w1 = z[u][1][q]*is4[u][q];
        float w2 = z[u][2][q]*is4[u][q];
        float w3 = z[u][3][q]*is4[u][q];
        if (act && lv){
          *(float4*)&wout[(((size_t)(b*4 + q))*NT + t)*NL + l0] =
              make_float4(w0, w1, w2, w3);
          uint2 pk;
          pk.x = (unsigned)f2bf(w0) | ((unsigned)f2bf(w1) << 16);
          pk.y = (unsigned)f2bf(w2) | ((unsigned)f2bf(w3) << 16);
          *(uint2*)&As[tl*AP + q*NL + l0] = pk;
        }
        wc[u][q*2 + 0] += w0*cv[u][0][0] + w1*cv[u][1][0] + w2*cv[u][2][0] + w3*cv[u][3][0];
        wc[u][q*2 + 1] += w0*cv[u][0][1] + w1*cv[u][1][1] + w2*cv[u][2][1] + w3*cv[u][3][1];
      }
    }
    #pragma unroll
    for (int u = 0; u < 2; ++u){
      if (u == 1 && !a1) break;
      #pragma unroll
      for (int x = 0; x < 8; ++x){
        float v = wc[u][x];
        #pragma unroll
        for (int off = 32; off; off >>= 1) v += __shfl_xor(v, off);
        wc[u][x] = v;
      }
      if (lane == 0){
        #pragma unroll
        for (int x = 0; x < 8; ++x) wcs[tl0 + u][x] = wc[u][x];
      }
    }
  }
  __syncthreads();

  // ------- phase 2: MFMA over K=800; each wave owns 16 Gt rows, 4 t-tiles -----
  f32x4 acc[4] = {};
  const ushort_t* Gb = Gt + (size_t)b*ND*800;
  for (int kt = 0; kt < 25; ++kt){
    int k0 = kt*32;
    bf16x8 afr[4], bfr;
    #pragma unroll
    for (int i = 0; i < 4; ++i)
      afr[i] = *(const bf16x8*)(&As[(i*16 + col)*AP + k0 + kg4*8]);
    bfr = *(const bf16x8*)(Gb + ((size_t)(wave*16 + col))*800 + k0 + kg4*8);
    #pragma unroll
    for (int i = 0; i < 4; ++i)
      acc[i] = __builtin_amdgcn_mfma_f32_16x16x32_bf16(afr[i], bfr, acc[i], 0, 0, 0);
  }
  __syncthreads();   // all waves done reading As -> safe to reuse as whc tile

  // ---- epilogue: whc[t][n] = fm*(vh + lbw + (lbc + wc.Lc)) -> LDS (stc) ----
  ushort_t (*stc)[264] = (ushort_t (*)[264])As;   // 64 x 264 bf16 (33.8KB)
  {
    int rq = lane >> 4;
    int n = wave*16 + col;
    float lbn = lbc[n], lbwn = lbw[n];
    float lcn[8];
    #pragma unroll
    for (int u = 0; u < 8; ++u) lcn[u] = Lc[u*ND + n];
    #pragma unroll
    for (int i = 0; i < 4; ++i){
      #pragma unroll
      for (int r = 0; r < 4; ++r){
        int tl = i*16 + rq*4 + r;
        int t = m0 + tl;
        if (t < NT){
          float f = (t < fl) ? 1.f : 0.f;
          float vcv = lbn
            + wcs[tl][0]*lcn[0] + wcs[tl][1]*lcn[1]
            + wcs[tl][2]*lcn[2] + wcs[tl][3]*lcn[3]
            + wcs[tl][4]*lcn[4] + wcs[tl][5]*lcn[5]
            + wcs[tl][6]*lcn[6] + wcs[tl][7]*lcn[7];
          stc[tl][n] = f2bf(f * (acc[i][r] + lbwn + vcv));
        }
      }
    }
  }
  __syncthreads();   // stc tile complete

  // -------- phase 3: out = WoT x stc^T (512 x 64 per block), from LDS --------
  {
    f32x4 acc2[2][4] = {};
    for (int kt = 0; kt < 8; ++kt){
      int k0 = kt*32;
      bf16x8 afr[2], bfr[4];
      #pragma unroll
      for (int j = 0; j < 4; ++j)
        bfr[j] = *(const bf16x8*)(&stc[j*16 + col][k0 + kg4*8]);
      #pragma unroll
      for (int i = 0; i < 2; ++i)
        afr[i] = *(const bf16x8*)(WoT + ((size_t)(wave*32 + i*16 + col))*ND + k0 + kg4*8);
      #pragma unroll
      for (int i = 0; i < 2; ++i)
        #pragma unroll
        for (int j = 0; j < 4; ++j)
          acc2[i][j] = __builtin_amdgcn_mfma_f32_16x16x32_bf16(afr[i], bfr[j], acc2[i][j], 0, 0, 0);
    }
    int rq = lane >> 4;
    #pragma unroll
    for (int i = 0; i < 2; ++i){
      #pragma unroll
      for (int r = 0; r < 4; ++r){
        int s = wave*32 + i*16 + rq*4 + r;
        float bov = bo[s];
        #pragma unroll
        for (int j = 0; j < 4; ++j){
          int t = m0 + j*16 + col;
          if (t < NT){
            float v = acc2[i][j][r] + bov;
            if (s < ND) o_mean[((size_t)b*ND + s)*NT + t] = v;
            else        o_lstd[((size_t)b*ND + (s - ND))*NT + t] = v;
          }
        }
      }
    }
  }
}

extern "C" void kernel_launch(void* const* d_in, const int* in_sizes, int n_in,
                              void* d_out, int out_size, void* d_ws, size_t ws_size,
                              hipStream_t stream)
{
  const float* dur = (const float*)d_in[0];
  const float* ph  = (const float*)d_in[1];
  // d_in[2] phoneme_mask: unused (pm == durations > 0)
  const float* Wpw = (const float*)d_in[3];
  const float* bpw = (const float*)d_in[4];
  const float* Cw  = (const float*)d_in[5];
  const float* cbw = (const float*)d_in[6];
  const float* Mw  = (const float*)d_in[7];
  const float* mbw = (const float*)d_in[8];
  const float* Lw  = (const float*)d_in[9];
  const float* lbw = (const float*)d_in[10];
  const float* Wpc = (const float*)d_in[11];
  const float* bpc = (const float*)d_in[12];
  const float* Cc  = (const float*)d_in[13];
  const float* cbc = (const float*)d_in[14];
  const float* Mc  = (const float*)d_in[15];
  const float* mbc = (const float*)d_in[16];
  const float* Lc  = (const float*)d_in[17];
  const float* lbc = (const float*)d_in[18];
  const float* Wo  = (const float*)d_in[19];
  const float* bo  = (const float*)d_in[20];

  float* out    = (float*)d_out;
  float* o_mean = out;
  float* o_lstd = out + (size_t)NB*ND*NT;
  float* o_fm   = o_lstd + (size_t)NB*ND*NT;
  float* o_fl   = o_fm + NB*NT;
  float* o_w    = o_fl + NB;

  float* ws   = (float*)d_ws;
  float* U_T  = ws + OFF_UT;
  float* Ct   = ws + OFF_CT;
  float* sk   = ws + OFF_SK;
  int*   fl   = (int*)(ws + OFF_FL);
  ushort_t* Gt   = (ushort_t*)(ws + OFF_GT);
  ushort_t* WoT  = (ushort_t*)(ws + OFF_WOT);

  k_pre<<<817, 256, 0, stream>>>(dur, ph, Wpw, Cw, bpw, Wpc, Cc, bpc, Wo, Lw,
                                 sk, fl, o_fm, o_fl, U_T, Ct, WoT, Gt);
  {
    dim3 g(NB, 16);   // flat id = b + 16*ttile  ->  XCD(id%8) = b%8
    k_wv_fused<<<g, 1024, 0, stream>>>(U_T, Ct, dur, sk, cbw, cbc, mbw, mbc,
                                       fl, Mw, Mc, Gt, Lc, lbc, lbw,
                                       WoT, bo, o_w, o_mean, o_lstd);
  }
}